// Round 10
// baseline (646.187 us; speedup 1.0000x reference)
//
#include <hip/hip_runtime.h>

// SpikingNN LIF scan: N=131072 traces x L=401 steps, fp32. Bit-exact vs ref.
//
// Round-8 = R6 config restored (256thr, 64KB LDS, exact 2 blocks/CU, 8
// waves/CU) + R7's dwordx4 stores + earliest-possible gll issue (top of
// iter, BEFORE the wait for the current chunk -> a full iteration of
// prefetch distance) + a flat-read PROBE dispatch to measure this
// machine's read ceiling (m13 pattern) under the same allocation.
//
// R7 post-mortem: regression was occupancy quantization (1024 blocks at 3
// blocks/CU -> 3+1 shifts; 6 waves/CU vs 8), not a refutation of depth.
// Counted-vmcnt ledger for this schedule (loads 32/chunk, stores 8/chunk),
// issue order: g0, [iter0: g1 | wait g0 | work | s0], [iter1: g2 | wait g1
// | work | s1], ...
//   c=0:        queue [g0 32][g1 32]            -> vmcnt(32)
//   1<=c<=11:   queue [gc 32][s(c-1) 8][g(c+1) 32] -> vmcnt(40)
//   c=12:       queue [g12 32][s11 8]           -> vmcnt(8)
// LDS swizzle (R6-proven, conflicts=0): slot s=k*64+lane holds
// (row=s>>5, col=(s&31)^(row&31)); gll source pre-swizzled, dest linear.
// Scan math in exact ref op order; i==0 folded via P=0, t_rest=-1.

#define L_STEPS 401
#define NCHUNK  13
#define CHUNK   32
#define BLKT    256
#define SLICE   (64 * CHUNK)           // 2048 dwords = 8 KB per buffer

typedef const __attribute__((address_space(1))) void* gas1_t;
typedef __attribute__((address_space(3))) void*       las3_t;
typedef float f4v __attribute__((ext_vector_type(4), aligned(4)));

__global__ __launch_bounds__(BLKT) void snn_scan_kernel(
    const float* __restrict__ S, float* __restrict__ out)
{
    __shared__ float smem[4][2][SLICE];        // 64 KB -> 2 blocks/CU exact

    const int tid       = threadIdx.x;
    const int wave      = tid >> 6;
    const int lane      = tid & 63;
    const int traceBase = blockIdx.x * BLKT + wave * 64;

    float P = 0.0f, t_rest = -1.0f;            // folds the i==0 branch

    auto stage = [&](int ccol, int b) {
        #pragma unroll
        for (int k = 0; k < 32; ++k) {
            const int s_  = k * 64 + lane;
            const int row = s_ >> 5;
            const int col = (s_ & 31) ^ (row & 31);
            int gc = ccol + col;
            if (gc > 400) gc = 400;            // tail clamp (dup, never stored)
            const float* gp = S + (size_t)(traceBase + row) * L_STEPS + gc;
            __builtin_amdgcn_global_load_lds(
                (gas1_t)gp, (las3_t)&smem[wave][b][k * 64], 4, 0, 0);
        }
    };

    stage(0, 0);

    #pragma unroll 1
    for (int c = 0; c < NCHUNK; ++c) {
        const int c0 = c * CHUNK;
        const int b  = c & 1;

        // ---- earliest-possible prefetch: issue gll_{c+1} BEFORE waiting ----
        // (buffer b^1 held chunk c-1; its store-phase ds_reads completed
        //  before those stores issued, i.e. before this point. Safe.)
        if (c + 1 < NCHUNK) stage(c0 + CHUNK, b ^ 1);
        asm volatile("" ::: "memory");

        if (c == 0)              asm volatile("s_waitcnt vmcnt(32)" ::: "memory");
        else if (c < NCHUNK - 1) asm volatile("s_waitcnt vmcnt(40)" ::: "memory");
        else                     asm volatile("s_waitcnt vmcnt(8)"  ::: "memory");

        // ---- read own row (swizzled, <=2-way = free) ----
        float sv[CHUNK];
        #pragma unroll
        for (int j = 0; j < CHUNK; ++j)
            sv[j] = smem[wave][b][lane * CHUNK + (j ^ (lane & 31))];

        // ---- LIF scan, exact ref op order (tail dup steps harmless) ----
        #pragma unroll
        for (int j = 0; j < CHUNK; ++j) {
            const float t = (float)(c0 + j) * 0.125f;          // exact in fp32
            float p = (t <= t_rest)
                    ? 0.0f
                    : ((P > -1.0f) ? (P + sv[j]) - 0.25f : 0.0f);
            const bool spike = (p >= 25.0f);
            t_rest = spike ? t + 5.0f : t_rest;                // exact in fp32
            p      = spike ? p + 4.0f : p;
            sv[j]  = p;
            P      = p;
        }

        // ---- write back (same swizzle) ----
        #pragma unroll
        for (int j = 0; j < CHUNK; ++j)
            smem[wave][b][lane * CHUNK + (j ^ (lane & 31))] = sv[j];

        asm volatile("" ::: "memory");

        // ---- store chunk c: 8 instrs of dwordx4 (gather 4 swizzled dwords) ----
        {
            const int q  = lane & 7;           // col-quad 0..7
            const int rb = lane >> 3;          // row offset 0..7
            #pragma unroll
            for (int k = 0; k < 8; ++k) {
                const int r  = 8 * k + rb;
                const int rx = r & 31;
                const float v0 = smem[wave][b][r * CHUNK + ((4 * q + 0) ^ rx)];
                const float v1 = smem[wave][b][r * CHUNK + ((4 * q + 1) ^ rx)];
                const float v2 = smem[wave][b][r * CHUNK + ((4 * q + 2) ^ rx)];
                const float v3 = smem[wave][b][r * CHUNK + ((4 * q + 3) ^ rx)];
                const int gc = c0 + 4 * q;
                float* op = out + (size_t)(traceBase + r) * L_STEPS + gc;
                if (gc + 3 <= 400) {                    // full quad (all c<12)
                    f4v v = {v0, v1, v2, v3};
                    *(f4v*)op = v;
                } else if (gc <= 400) {                 // tail: col 400 only
                    op[0] = v0;
                    if (gc + 1 <= 400) op[1] = v1;
                    if (gc + 2 <= 400) op[2] = v2;
                }
            }
        }
        asm volatile("" ::: "memory");
    }
}

// ---- diagnostic probe: m13-pattern flat float4 read of S (205 MB) ----
// Own rocprof row => machine's read ceiling for this allocation. Sum is
// sunk via one atomicAdd per wave into d_ws (never validated).
__global__ __launch_bounds__(256) void probe_read_kernel(
    const float4* __restrict__ in, float* __restrict__ ws, long n4)
{
    float acc = 0.0f;
    const long stride = (long)gridDim.x * blockDim.x;
    for (long i = (long)blockIdx.x * blockDim.x + threadIdx.x; i < n4; i += stride) {
        const float4 v = in[i];
        acc += v.x + v.y + v.z + v.w;
    }
    #pragma unroll
    for (int off = 32; off; off >>= 1) acc += __shfl_down(acc, off, 64);
    if ((threadIdx.x & 63) == 0) atomicAdd(ws, acc);
}

extern "C" void kernel_launch(void* const* d_in, const int* in_sizes, int n_in,
                              void* d_out, int out_size, void* d_ws, size_t ws_size,
                              hipStream_t stream)
{
    // d_in[0] = Pn (dead in reference), d_in[1] = S
    const float* S   = (const float*)d_in[1];
    float*       out = (float*)d_out;

    snn_scan_kernel<<<(131072 / BLKT), BLKT, 0, stream>>>(S, out);

    // Diagnostic probe (adds ~35-90us to headline; read ceiling measurement).
    const long n4 = (long)131072 * L_STEPS / 4;   // 13,139,968 float4
    probe_read_kernel<<<2048, 256, 0, stream>>>(
        (const float4*)S, (float*)d_ws, n4);
}